// Round 7
// baseline (331.548 us; speedup 1.0000x reference)
//
#include <hip/hip_runtime.h>
#include <stdint.h>

#define BATCH 32
#define CIN   8
#define NCH   128   // 4*F_DIM
#define PP    128   // P
#define NSTRIP 8    // k1 strips per batch (16 p each)
#define KSTRIP 16   // k2 strips per batch (8 p each)

typedef __attribute__((ext_vector_type(8))) short    bf16x8;
typedef __attribute__((ext_vector_type(4))) float    f32x4;

__device__ __forceinline__ float bf2f(unsigned short u) {
    union { unsigned int i; float f; } x; x.i = ((unsigned int)u) << 16; return x.f;
}
__device__ __forceinline__ unsigned short f2bf(float f) {
    union { float f; unsigned int i; } x; x.f = f;
    unsigned int r = x.i + 0x7fffu + ((x.i >> 16) & 1u);
    return (unsigned short)(r >> 16);
}
__device__ __forceinline__ unsigned int pk2(float a, float b) {
    return (unsigned int)f2bf(a) | ((unsigned int)f2bf(b) << 16);
}

// Swizzled byte offset into a [128 rows][128 bf16] LDS tile (row = 256 B).
#define SWZB(row, cb) (((row) << 8) + ((cb) ^ (((row) & 7) << 4)))

// ---------------------------------------------------------------------------
// K1: RS1t[b][p][c] = sum_q t ; CS1p[b][strip][c][q] = partial sum_p t.
// t = relu(W1.phi + b1).  Grid: 32 b x 8 strips (16 p each), 512 threads.
// ---------------------------------------------------------------------------
__global__ __launch_bounds__(512) void k1_sums(const float* __restrict__ phi,
        const float* __restrict__ W1, const float* __restrict__ b1,
        float* __restrict__ RS1t, float* __restrict__ CS1p) {
    __shared__ float S[17408];
    int bx = blockIdx.x;
    int b = bx >> 3, strip = bx & 7;
    int p0 = strip * 16;
    int tid = threadIdx.x;
    int c = tid & 127, qq = tid >> 7;

    #pragma unroll
    for (int i = 0; i < 8; ++i) {
        int idx = tid + i * 512;                 // float4 index
        int pi = idx >> 8, ci = (idx >> 5) & 7, q4 = (idx & 31) * 4;
        float4 v = *(const float4*)(phi + ((size_t)(b * CIN + ci) * PP + p0 + pi) * PP + q4);
        *(float4*)(S + pi * 1024 + ci * 128 + q4) = v;
    }
    float4 w1a = *(const float4*)(W1 + c * 8);
    float4 w1b = *(const float4*)(W1 + c * 8 + 4);
    float b1c = b1[c];
    float cs_acc[32];
    #pragma unroll
    for (int j = 0; j < 32; ++j) cs_acc[j] = 0.f;
    float rsp[16];
    __syncthreads();

    for (int pi = 0; pi < 16; ++pi) {
        float rs = 0.f;
        const float* pb = S + pi * 1024;
        #pragma unroll
        for (int j4 = 0; j4 < 8; ++j4) {
            int q4 = qq * 32 + j4 * 4;
            float4 ph[8];
            #pragma unroll
            for (int ci = 0; ci < 8; ++ci)
                ph[ci] = *(const float4*)(pb + ci * 128 + q4);
            #pragma unroll
            for (int e = 0; e < 4; ++e) {
                float t = b1c;
                t = fmaf(w1a.x, ((const float*)&ph[0])[e], t);
                t = fmaf(w1a.y, ((const float*)&ph[1])[e], t);
                t = fmaf(w1a.z, ((const float*)&ph[2])[e], t);
                t = fmaf(w1a.w, ((const float*)&ph[3])[e], t);
                t = fmaf(w1b.x, ((const float*)&ph[4])[e], t);
                t = fmaf(w1b.y, ((const float*)&ph[5])[e], t);
                t = fmaf(w1b.z, ((const float*)&ph[6])[e], t);
                t = fmaf(w1b.w, ((const float*)&ph[7])[e], t);
                t = fmaxf(t, 0.f);
                cs_acc[j4 * 4 + e] += t;
                rs += t;
            }
        }
        rsp[pi] = rs;
    }
    __syncthreads();
    #pragma unroll
    for (int pi = 0; pi < 16; ++pi) S[pi * 512 + tid] = rsp[pi];
    __syncthreads();
    #pragma unroll
    for (int i = 0; i < 4; ++i) {
        int idx = tid + i * 512;
        int pi = idx >> 7, cc = idx & 127;
        float s = S[pi * 512 + cc] + S[pi * 512 + 128 + cc]
                + S[pi * 512 + 256 + cc] + S[pi * 512 + 384 + cc];
        RS1t[((size_t)b * PP + p0 + pi) * NCH + cc] = s;
    }
    __syncthreads();
    #pragma unroll
    for (int j4 = 0; j4 < 8; ++j4) {
        float4 v = {cs_acc[j4 * 4], cs_acc[j4 * 4 + 1], cs_acc[j4 * 4 + 2], cs_acc[j4 * 4 + 3]};
        *(float4*)(S + c * 132 + qq * 32 + j4 * 4) = v;
    }
    __syncthreads();
    float* dstp = CS1p + (size_t)(b * NSTRIP + strip) * NCH * PP;
    for (int k = tid; k < 16384; k += 512) {
        int cc = k >> 7, q = k & 127;
        dstp[k] = S[cc * 132 + q];
    }
}

// ---------------------------------------------------------------------------
// K1b: Ap[b][o][q], Bqt[b][p][o] (with Cc folded in), W3bf (block 0).
// Grid: 32 b x 4 o-groups, 256 threads.
// ---------------------------------------------------------------------------
__global__ __launch_bounds__(256) void k1b_planes(const float* __restrict__ W3,
        const float* __restrict__ b3, const float* __restrict__ RS1t,
        const float* __restrict__ CS1p, float* __restrict__ Ap,
        float* __restrict__ Bqt, unsigned short* __restrict__ W3bf) {
    int bx = blockIdx.x;
    int b = bx >> 2, og = bx & 3;
    int tid = threadIdx.x;
    __shared__ float cs_g[64][132];   // rows 0..31 -> ch 32+r ; 32..63 -> ch 96..127
    __shared__ float rs_g[64][132];   // rows r -> ch 64+r
    __shared__ float s1_96[32];
    for (int k = tid; k < 64 * 128; k += 256) {
        int r = k >> 7, q = k & 127;
        int ch_c = (r < 32) ? (32 + r) : (64 + r);
        float s = 0.f;
        #pragma unroll
        for (int s8 = 0; s8 < NSTRIP; ++s8)
            s += CS1p[((size_t)(b * NSTRIP + s8) * NCH + ch_c) * PP + q];
        cs_g[r][q] = s;
    }
    for (int k = tid; k < 64 * 128; k += 256) {
        int p = k >> 6, r = k & 63;
        rs_g[r][p] = RS1t[((size_t)b * PP + p) * NCH + 64 + r];
    }
    __syncthreads();
    if (tid < 32) {
        float s = 0.f;
        for (int q = 0; q < 128; ++q) s += cs_g[32 + tid][q];
        s1_96[tid] = s;
    }
    int o = og * 32 + (tid >> 3), qh = tid & 7;
    {
        float wa[64];
        #pragma unroll
        for (int r = 0; r < 64; ++r)
            wa[r] = (r < 32) ? W3[o * NCH + 32 + r] * (1.f / 3.f)
                             : -W3[o * NCH + 64 + r] * (1.f / 9.f);
        #pragma unroll
        for (int j = 0; j < 4; ++j) {
            int q = qh * 16 + j * 4;
            float4 a = {0.f, 0.f, 0.f, 0.f};
            #pragma unroll
            for (int r = 0; r < 64; ++r) {
                float4 cv = *(const float4*)&cs_g[r][q];
                a.x = fmaf(wa[r], cv.x, a.x);
                a.y = fmaf(wa[r], cv.y, a.y);
                a.z = fmaf(wa[r], cv.z, a.z);
                a.w = fmaf(wa[r], cv.w, a.w);
            }
            *(float4*)&Ap[((size_t)b * NCH + o) * PP + q] = a;
        }
    }
    __syncthreads();
    float cc = b3[o];
    #pragma unroll
    for (int r = 0; r < 32; ++r)
        cc = fmaf(W3[o * NCH + 96 + r] * (1.f / 9.f), s1_96[r], cc);
    {
        float wb[64];
        #pragma unroll
        for (int r = 0; r < 64; ++r)
            wb[r] = (r < 32) ? W3[o * NCH + 64 + r] * (1.f / 3.f)
                             : -W3[o * NCH + 64 + r] * (1.f / 9.f);
        #pragma unroll
        for (int j = 0; j < 4; ++j) {
            int p4 = qh * 16 + j * 4;
            float4 a = {0.f, 0.f, 0.f, 0.f};
            #pragma unroll
            for (int r = 0; r < 64; ++r) {
                float4 rv = *(const float4*)&rs_g[r][p4];
                a.x = fmaf(wb[r], rv.x, a.x);
                a.y = fmaf(wb[r], rv.y, a.y);
                a.z = fmaf(wb[r], rv.z, a.z);
                a.w = fmaf(wb[r], rv.w, a.w);
            }
            Bqt[((size_t)b * PP + p4 + 0) * NCH + o] = a.x + cc;
            Bqt[((size_t)b * PP + p4 + 1) * NCH + o] = a.y + cc;
            Bqt[((size_t)b * PP + p4 + 2) * NCH + o] = a.z + cc;
            Bqt[((size_t)b * PP + p4 + 3) * NCH + o] = a.w + cc;
        }
    }
    if (bx == 0) {
        for (int i = 0; i < 16; ++i) {
            int k = tid + i * 256;
            float4 w = *(const float4*)(W3 + k * 4);
            int c0 = (k * 4) & 127;
            float sc = (c0 < 32) ? 1.f : ((c0 < 96) ? (-1.f / 3.f) : (1.f / 9.f));
            unsigned int lo = pk2(w.x * sc, w.y * sc);
            unsigned int hi = pk2(w.z * sc, w.w * sc);
            uint2 u = {lo, hi};
            *(uint2*)(W3bf + k * 4) = u;
        }
    }
}

// ---------------------------------------------------------------------------
// K2a: v-SUMS pass (no v materialization).  Grid 32 b x 16 strips, 512 thr.
// Per row: t-GEMM1 -> GEMM2 (nt 2..7 only) -> relu -> reduce:
//  RSvT[b][p][jr] (jr = o-64, 0..63), block-owned, plain store;
//  CSp[b][strip][jc][q] (jc: o32..63 -> 0..31, o96..127 -> 32..63),
//  accumulated in registers across the 8 rows.
// ---------------------------------------------------------------------------
__global__ __launch_bounds__(512, 4) void k2a_sums(const float* __restrict__ phi,
        const float* __restrict__ W1, const float* __restrict__ b1,
        const unsigned short* __restrict__ W3bf,
        const float* __restrict__ Ap, const float* __restrict__ Bqt,
        float* __restrict__ RSvT, float* __restrict__ CSp) {
    int bx = blockIdx.x;
    int b = bx >> 4, strip = bx & 15;
    int p0 = strip * 8;
    __shared__ unsigned short w3_l[16384];
    __shared__ unsigned short t_l[16384];
    __shared__ unsigned short phi_b[2][1024];
    __shared__ float BC_l[2][128];
    __shared__ float rs_part[8][64];
    int tid = threadIdx.x;
    int wv = tid >> 6, l = tid & 63, lr = l & 15, lg = l >> 4;
    int q0 = wv * 16 + lg * 4;

    #pragma unroll
    for (int i = 0; i < 4; ++i) {
        int k = tid + i * 512;
        int o = k >> 4, cb = (k & 15) * 16;
        bf16x8 v = *(const bf16x8*)(W3bf + k * 8);
        *(bf16x8*)((char*)w3_l + SWZB(o, cb)) = v;
    }
    bf16x8 w1fr = {0, 0, 0, 0, 0, 0, 0, 0};
    if (lg == 0) {
        int cc = wv * 16 + lr;
        float4 wa = *(const float4*)(W1 + cc * 8);
        float4 wb = *(const float4*)(W1 + cc * 8 + 4);
        w1fr[0] = (short)f2bf(wa.x); w1fr[1] = (short)f2bf(wa.y);
        w1fr[2] = (short)f2bf(wa.z); w1fr[3] = (short)f2bf(wa.w);
        w1fr[4] = (short)f2bf(wb.x); w1fr[5] = (short)f2bf(wb.y);
        w1fr[6] = (short)f2bf(wb.z); w1fr[7] = (short)f2bf(wb.w);
    }
    int c0 = wv * 16 + lg * 4;
    f32x4 binit = {b1[c0], b1[c0 + 1], b1[c0 + 2], b1[c0 + 3]};
    if (tid < 128) {
        bf16x8 pv;
        #pragma unroll
        for (int ci = 0; ci < 8; ++ci)
            pv[ci] = (short)f2bf(phi[((size_t)(b * CIN + ci) * PP + p0) * PP + tid]);
        *(bf16x8*)(phi_b[0] + tid * 8) = pv;
        BC_l[0][tid] = Bqt[((size_t)b * PP + p0) * NCH + tid];
    }
    __syncthreads();

    f32x4 cs_acc[4];
    #pragma unroll
    for (int i = 0; i < 4; ++i) { f32x4 z = {0.f, 0.f, 0.f, 0.f}; cs_acc[i] = z; }

    for (int r = 0; r < 8; ++r) {
        int cur = r & 1, nxt = cur ^ 1;
        int p = p0 + r;
        float pfv[8]; float bcn = 0.f;
        if (r < 7 && tid < 128) {
            #pragma unroll
            for (int ci = 0; ci < 8; ++ci)
                pfv[ci] = phi[((size_t)(b * CIN + ci) * PP + p + 1) * PP + tid];
            bcn = Bqt[((size_t)b * PP + p + 1) * NCH + tid];
        }
        // GEMM1
        const unsigned short* pb = phi_b[cur];
        #pragma unroll
        for (int pt = 0; pt < 8; ++pt) {
            int pix = pt * 16 + lr;
            bf16x8 bfr1 = {0, 0, 0, 0, 0, 0, 0, 0};
            if (lg == 0) bfr1 = *(const bf16x8*)(pb + pix * 8);
            f32x4 a = __builtin_amdgcn_mfma_f32_16x16x32_bf16(w1fr, bfr1, binit, 0, 0, 0);
            uint2 u;
            u.x = pk2(fmaxf(a.x, 0.f), fmaxf(a.y, 0.f));
            u.y = pk2(fmaxf(a.z, 0.f), fmaxf(a.w, 0.f));
            *(uint2*)((char*)t_l + SWZB(pix, c0 * 2)) = u;
        }
        __syncthreads();
        bf16x8 afr[4];
        #pragma unroll
        for (int ks = 0; ks < 4; ++ks)
            afr[ks] = *(const bf16x8*)((char*)t_l + SWZB(wv * 16 + lr, ks * 64 + lg * 16));
        #pragma unroll
        for (int nt = 2; nt < 8; ++nt) {
            int o = nt * 16 + lr;
            bf16x8 bfr[4];
            #pragma unroll
            for (int ks = 0; ks < 4; ++ks)
                bfr[ks] = *(const bf16x8*)((char*)w3_l + SWZB(o, ks * 64 + lg * 16));
            f32x4 ap = *(const f32x4*)(Ap + ((size_t)(b * NCH + o)) * PP + q0);
            f32x4 acc = ap + BC_l[cur][o];
            #pragma unroll
            for (int ks = 0; ks < 4; ++ks)
                acc = __builtin_amdgcn_mfma_f32_16x16x32_bf16(afr[ks], bfr[ks], acc, 0, 0, 0);
            f32x4 v = {fmaxf(acc.x, 0.f), fmaxf(acc.y, 0.f), fmaxf(acc.z, 0.f), fmaxf(acc.w, 0.f)};
            if (nt < 4) cs_acc[nt - 2] += v;
            else if (nt >= 6) cs_acc[nt - 4] += v;
            if (nt >= 4) {
                float rsv = v.x + v.y + v.z + v.w;
                rsv += __shfl_xor(rsv, 16);
                rsv += __shfl_xor(rsv, 32);
                if (lg == 0) rs_part[wv][(nt - 4) * 16 + lr] = rsv;
            }
        }
        if (r < 7 && tid < 128) {
            bf16x8 pv;
            #pragma unroll
            for (int ci = 0; ci < 8; ++ci) pv[ci] = (short)f2bf(pfv[ci]);
            *(bf16x8*)(phi_b[nxt] + tid * 8) = pv;
            BC_l[nxt][tid] = bcn;
        }
        __syncthreads();
        if (tid < 64) {
            float s = 0.f;
            #pragma unroll
            for (int w8 = 0; w8 < 8; ++w8) s += rs_part[w8][tid];
            RSvT[((size_t)(b * PP + p)) * 64 + tid] = s;
        }
    }
    // store cs strip-partials: jc mapping nt2->lr, nt3->16+lr, nt6->32+lr, nt7->48+lr
    {
        float* dst = CSp + ((size_t)(b * KSTRIP + strip)) * 64 * PP;
        *(f32x4*)(dst + (size_t)(lr)      * PP + q0) = cs_acc[0];
        *(f32x4*)(dst + (size_t)(16 + lr) * PP + q0) = cs_acc[1];
        *(f32x4*)(dst + (size_t)(32 + lr) * PP + q0) = cs_acc[2];
        *(f32x4*)(dst + (size_t)(48 + lr) * PP + q0) = cs_acc[3];
    }
}

// ---------------------------------------------------------------------------
// K2s: reduce strip partials.  CSv[b][jc][q] = sum_strip CSp; Sb[b][jo] =
// sum_p RSvT[b][p][32+jo].  Grid 32, 256 threads.
// ---------------------------------------------------------------------------
__global__ __launch_bounds__(256) void k2s_reduce(const float* __restrict__ CSp,
        const float* __restrict__ RSvT, float* __restrict__ CSv,
        float* __restrict__ Sb) {
    int b = blockIdx.x, tid = threadIdx.x;
    for (int k = tid; k < 64 * PP; k += 256) {
        float s = 0.f;
        #pragma unroll
        for (int st = 0; st < KSTRIP; ++st)
            s += CSp[((size_t)(b * KSTRIP + st)) * 64 * PP + k];
        CSv[(size_t)b * 64 * PP + k] = s;
    }
    if (tid < 32) {
        float s = 0.f;
        for (int p = 0; p < PP; ++p) s += RSvT[((size_t)(b * PP + p)) * 64 + 32 + tid];
        Sb[b * 32 + tid] = s;
    }
}

// ---------------------------------------------------------------------------
// K2b: OUTPUT pass.  Recomputes v via the same MFMA pipeline and applies the
// postprocess in the epilogue, writing out directly (f32, 268 MB), using
// RSvT/CSv/Sb.  Grid 32 b x 16 strips, 512 threads.
// ---------------------------------------------------------------------------
__global__ __launch_bounds__(512, 4) void k2b_out(const float* __restrict__ phi,
        const float* __restrict__ W1, const float* __restrict__ b1,
        const unsigned short* __restrict__ W3bf,
        const float* __restrict__ Ap, const float* __restrict__ Bqt,
        const float* __restrict__ RSvT, const float* __restrict__ CSv,
        const float* __restrict__ Sb, float* __restrict__ out) {
    int bx = blockIdx.x;
    int b = bx >> 4, strip = bx & 15;
    int p0 = strip * 8;
    __shared__ unsigned short w3_l[16384];
    __shared__ unsigned short t_l[16384];
    __shared__ unsigned short phi_b[2][1024];
    __shared__ float BC_l[2][128];
    __shared__ float rs_l[2][64];
    __shared__ float S_l[32];
    int tid = threadIdx.x;
    int wv = tid >> 6, l = tid & 63, lr = l & 15, lg = l >> 4;
    int q0 = wv * 16 + lg * 4;

    #pragma unroll
    for (int i = 0; i < 4; ++i) {
        int k = tid + i * 512;
        int o = k >> 4, cb = (k & 15) * 16;
        bf16x8 v = *(const bf16x8*)(W3bf + k * 8);
        *(bf16x8*)((char*)w3_l + SWZB(o, cb)) = v;
    }
    bf16x8 w1fr = {0, 0, 0, 0, 0, 0, 0, 0};
    if (lg == 0) {
        int cc = wv * 16 + lr;
        float4 wa = *(const float4*)(W1 + cc * 8);
        float4 wb = *(const float4*)(W1 + cc * 8 + 4);
        w1fr[0] = (short)f2bf(wa.x); w1fr[1] = (short)f2bf(wa.y);
        w1fr[2] = (short)f2bf(wa.z); w1fr[3] = (short)f2bf(wa.w);
        w1fr[4] = (short)f2bf(wb.x); w1fr[5] = (short)f2bf(wb.y);
        w1fr[6] = (short)f2bf(wb.z); w1fr[7] = (short)f2bf(wb.w);
    }
    int c0 = wv * 16 + lg * 4;
    f32x4 binit = {b1[c0], b1[c0 + 1], b1[c0 + 2], b1[c0 + 3]};
    if (tid < 128) {
        bf16x8 pv;
        #pragma unroll
        for (int ci = 0; ci < 8; ++ci)
            pv[ci] = (short)f2bf(phi[((size_t)(b * CIN + ci) * PP + p0) * PP + tid]);
        *(bf16x8*)(phi_b[0] + tid * 8) = pv;
        BC_l[0][tid] = Bqt[((size_t)b * PP + p0) * NCH + tid];
    } else if (tid < 192) {
        rs_l[0][tid - 128] = RSvT[((size_t)(b * PP + p0)) * 64 + tid - 128];
    } else if (tid < 224) {
        S_l[tid - 192] = Sb[b * 32 + tid - 192];
    }
    __syncthreads();

    for (int r = 0; r < 8; ++r) {
        int cur = r & 1, nxt = cur ^ 1;
        int p = p0 + r;
        float pfv[8]; float bcn = 0.f; float rsn = 0.f;
        if (r < 7) {
            if (tid < 128) {
                #pragma unroll
                for (int ci = 0; ci < 8; ++ci)
                    pfv[ci] = phi[((size_t)(b * CIN + ci) * PP + p + 1) * PP + tid];
                bcn = Bqt[((size_t)b * PP + p + 1) * NCH + tid];
            } else if (tid < 192) {
                rsn = RSvT[((size_t)(b * PP + p + 1)) * 64 + tid - 128];
            }
        }
        // GEMM1
        const unsigned short* pb = phi_b[cur];
        #pragma unroll
        for (int pt = 0; pt < 8; ++pt) {
            int pix = pt * 16 + lr;
            bf16x8 bfr1 = {0, 0, 0, 0, 0, 0, 0, 0};
            if (lg == 0) bfr1 = *(const bf16x8*)(pb + pix * 8);
            f32x4 a = __builtin_amdgcn_mfma_f32_16x16x32_bf16(w1fr, bfr1, binit, 0, 0, 0);
            uint2 u;
            u.x = pk2(fmaxf(a.x, 0.f), fmaxf(a.y, 0.f));
            u.y = pk2(fmaxf(a.z, 0.f), fmaxf(a.w, 0.f));
            *(uint2*)((char*)t_l + SWZB(pix, c0 * 2)) = u;
        }
        __syncthreads();
        bf16x8 afr[4];
        #pragma unroll
        for (int ks = 0; ks < 4; ++ks)
            afr[ks] = *(const bf16x8*)((char*)t_l + SWZB(wv * 16 + lr, ks * 64 + lg * 16));
        #pragma unroll
        for (int nt = 0; nt < 8; ++nt) {
            int o = nt * 16 + lr;
            bf16x8 bfr[4];
            #pragma unroll
            for (int ks = 0; ks < 4; ++ks)
                bfr[ks] = *(const bf16x8*)((char*)w3_l + SWZB(o, ks * 64 + lg * 16));
            f32x4 ap = *(const f32x4*)(Ap + ((size_t)(b * NCH + o)) * PP + q0);
            f32x4 acc = ap + BC_l[cur][o];
            #pragma unroll
            for (int ks = 0; ks < 4; ++ks)
                acc = __builtin_amdgcn_mfma_f32_16x16x32_bf16(afr[ks], bfr[ks], acc, 0, 0, 0);
            f32x4 v = {fmaxf(acc.x, 0.f), fmaxf(acc.y, 0.f), fmaxf(acc.z, 0.f), fmaxf(acc.w, 0.f)};
            f32x4 o4;
            if (nt < 2) {
                o4 = v;
            } else if (nt < 4) {
                f32x4 cs = *(const f32x4*)(CSv + ((size_t)b * 64 + (nt - 2) * 16 + lr) * PP + q0);
                o4 = (cs - v) * (1.f / 3.f);
            } else if (nt < 6) {
                float rp = rs_l[cur][(nt - 4) * 16 + lr];
                o4 = (rp - v) * (1.f / 3.f);
            } else {
                int jr = (nt - 4) * 16 + lr;
                float rp = rs_l[cur][jr];
                float sj = S_l[jr - 32];
                f32x4 cs = *(const f32x4*)(CSv + ((size_t)b * 64 + 32 + (nt - 6) * 16 + lr) * PP + q0);
                o4 = ((sj - rp) - cs + v) * (1.f / 9.f);
            }
            *(f32x4*)(out + ((size_t)(b * NCH + o) * PP + p) * PP + q0) = o4;
        }
        if (r < 7) {
            if (tid < 128) {
                bf16x8 pv;
                #pragma unroll
                for (int ci = 0; ci < 8; ++ci) pv[ci] = (short)f2bf(pfv[ci]);
                *(bf16x8*)(phi_b[nxt] + tid * 8) = pv;
                BC_l[nxt][tid] = bcn;
            } else if (tid < 192) {
                rs_l[nxt][tid - 128] = rsn;
            }
        }
        __syncthreads();
    }
}

// ---------------------------------------------------------------------------
extern "C" void kernel_launch(void* const* d_in, const int* in_sizes, int n_in,
                              void* d_out, int out_size, void* d_ws, size_t ws_size,
                              hipStream_t stream) {
    (void)in_sizes; (void)n_in; (void)out_size; (void)ws_size;
    const float* phi = (const float*)d_in[0];
    const float* W1  = (const float*)d_in[1];
    const float* b1  = (const float*)d_in[2];
    const float* W3  = (const float*)d_in[3];
    const float* b3  = (const float*)d_in[4];
    float* out = (float*)d_out;

    char* ws = (char*)d_ws;
    size_t off = 0;
    float* RS1t = (float*)(ws + off); off += (size_t)BATCH * NCH * PP * 4;            // 2 MB
    float* CS1p = (float*)(ws + off); off += (size_t)BATCH * NSTRIP * NCH * PP * 4;   // 16 MB
    float* Ap   = (float*)(ws + off); off += (size_t)BATCH * NCH * PP * 4;            // 8 MB
    float* Bqt  = (float*)(ws + off); off += (size_t)BATCH * NCH * PP * 4;            // 8 MB
    unsigned short* W3bf = (unsigned short*)(ws + off); off += (size_t)NCH * NCH * 2; // 32 KB
    float* RSvT = (float*)(ws + off); off += (size_t)BATCH * PP * 64 * 4;             // 1 MB
    float* CSp  = (float*)(ws + off); off += (size_t)BATCH * KSTRIP * 64 * PP * 4;    // 16 MB
    float* CSv  = (float*)(ws + off); off += (size_t)BATCH * 64 * PP * 4;             // 1 MB
    float* Sb   = (float*)(ws + off); off += (size_t)BATCH * 32 * 4;                  // 4 KB

    k1_sums<<<BATCH * NSTRIP, 512, 0, stream>>>(phi, W1, b1, RS1t, CS1p);
    k1b_planes<<<BATCH * 4, 256, 0, stream>>>(W3, b3, RS1t, CS1p, Ap, Bqt, W3bf);
    k2a_sums<<<BATCH * KSTRIP, 512, 0, stream>>>(phi, W1, b1, W3bf, Ap, Bqt, RSvT, CSp);
    k2s_reduce<<<BATCH, 256, 0, stream>>>(CSp, RSvT, CSv, Sb);
    k2b_out<<<BATCH * KSTRIP, 512, 0, stream>>>(phi, W1, b1, W3bf, Ap, Bqt, RSvT, CSv, Sb, out);
}

// Round 8
// 319.752 us; speedup vs baseline: 1.0369x; 1.0369x over previous
//
#include <hip/hip_runtime.h>
#include <stdint.h>

#define BATCH 32
#define CIN   8
#define NCH   128   // 4*F_DIM
#define PP    128   // P
#define NSTRIP 8    // k1 strips per batch (16 p each)
#define KSTRIP 16   // k2 strips per batch (8 p each)

typedef __attribute__((ext_vector_type(8))) short    bf16x8;
typedef __attribute__((ext_vector_type(4))) float    f32x4;

__device__ __forceinline__ float bf2f(unsigned short u) {
    union { unsigned int i; float f; } x; x.i = ((unsigned int)u) << 16; return x.f;
}
__device__ __forceinline__ unsigned short f2bf(float f) {
    union { float f; unsigned int i; } x; x.f = f;
    unsigned int r = x.i + 0x7fffu + ((x.i >> 16) & 1u);
    return (unsigned short)(r >> 16);
}
__device__ __forceinline__ unsigned int pk2(float a, float b) {
    return (unsigned int)f2bf(a) | ((unsigned int)f2bf(b) << 16);
}

// Swizzled byte offset into a [128 rows][128 bf16] LDS tile (row = 256 B).
#define SWZB(row, cb) (((row) << 8) + ((cb) ^ (((row) & 7) << 4)))

// ---------------------------------------------------------------------------
// K1: RS1t[b][p][c] = sum_q t ; CS1p[b][strip][c][q] = partial sum_p t.
// ---------------------------------------------------------------------------
__global__ __launch_bounds__(512) void k1_sums(const float* __restrict__ phi,
        const float* __restrict__ W1, const float* __restrict__ b1,
        float* __restrict__ RS1t, float* __restrict__ CS1p) {
    __shared__ float S[17408];
    int bx = blockIdx.x;
    int b = bx >> 3, strip = bx & 7;
    int p0 = strip * 16;
    int tid = threadIdx.x;
    int c = tid & 127, qq = tid >> 7;

    #pragma unroll
    for (int i = 0; i < 8; ++i) {
        int idx = tid + i * 512;                 // float4 index
        int pi = idx >> 8, ci = (idx >> 5) & 7, q4 = (idx & 31) * 4;
        float4 v = *(const float4*)(phi + ((size_t)(b * CIN + ci) * PP + p0 + pi) * PP + q4);
        *(float4*)(S + pi * 1024 + ci * 128 + q4) = v;
    }
    float4 w1a = *(const float4*)(W1 + c * 8);
    float4 w1b = *(const float4*)(W1 + c * 8 + 4);
    float b1c = b1[c];
    float cs_acc[32];
    #pragma unroll
    for (int j = 0; j < 32; ++j) cs_acc[j] = 0.f;
    float rsp[16];
    __syncthreads();

    for (int pi = 0; pi < 16; ++pi) {
        float rs = 0.f;
        const float* pb = S + pi * 1024;
        #pragma unroll
        for (int j4 = 0; j4 < 8; ++j4) {
            int q4 = qq * 32 + j4 * 4;
            float4 ph[8];
            #pragma unroll
            for (int ci = 0; ci < 8; ++ci)
                ph[ci] = *(const float4*)(pb + ci * 128 + q4);
            #pragma unroll
            for (int e = 0; e < 4; ++e) {
                float t = b1c;
                t = fmaf(w1a.x, ((const float*)&ph[0])[e], t);
                t = fmaf(w1a.y, ((const float*)&ph[1])[e], t);
                t = fmaf(w1a.z, ((const float*)&ph[2])[e], t);
                t = fmaf(w1a.w, ((const float*)&ph[3])[e], t);
                t = fmaf(w1b.x, ((const float*)&ph[4])[e], t);
                t = fmaf(w1b.y, ((const float*)&ph[5])[e], t);
                t = fmaf(w1b.z, ((const float*)&ph[6])[e], t);
                t = fmaf(w1b.w, ((const float*)&ph[7])[e], t);
                t = fmaxf(t, 0.f);
                cs_acc[j4 * 4 + e] += t;
                rs += t;
            }
        }
        rsp[pi] = rs;
    }
    __syncthreads();
    #pragma unroll
    for (int pi = 0; pi < 16; ++pi) S[pi * 512 + tid] = rsp[pi];
    __syncthreads();
    #pragma unroll
    for (int i = 0; i < 4; ++i) {
        int idx = tid + i * 512;
        int pi = idx >> 7, cc = idx & 127;
        float s = S[pi * 512 + cc] + S[pi * 512 + 128 + cc]
                + S[pi * 512 + 256 + cc] + S[pi * 512 + 384 + cc];
        RS1t[((size_t)b * PP + p0 + pi) * NCH + cc] = s;
    }
    __syncthreads();
    #pragma unroll
    for (int j4 = 0; j4 < 8; ++j4) {
        float4 v = {cs_acc[j4 * 4], cs_acc[j4 * 4 + 1], cs_acc[j4 * 4 + 2], cs_acc[j4 * 4 + 3]};
        *(float4*)(S + c * 132 + qq * 32 + j4 * 4) = v;
    }
    __syncthreads();
    float* dstp = CS1p + (size_t)(b * NSTRIP + strip) * NCH * PP;
    for (int k = tid; k < 16384; k += 512) {
        int cc = k >> 7, q = k & 127;
        dstp[k] = S[cc * 132 + q];
    }
}

// ---------------------------------------------------------------------------
// K1b: Ap[b][o][q], Bqt[b][p][o] (with Cc folded in), W3bf (block 0).
// ---------------------------------------------------------------------------
__global__ __launch_bounds__(256) void k1b_planes(const float* __restrict__ W3,
        const float* __restrict__ b3, const float* __restrict__ RS1t,
        const float* __restrict__ CS1p, float* __restrict__ Ap,
        float* __restrict__ Bqt, unsigned short* __restrict__ W3bf) {
    int bx = blockIdx.x;
    int b = bx >> 2, og = bx & 3;
    int tid = threadIdx.x;
    __shared__ float cs_g[64][132];
    __shared__ float rs_g[64][132];
    __shared__ float s1_96[32];
    for (int k = tid; k < 64 * 128; k += 256) {
        int r = k >> 7, q = k & 127;
        int ch_c = (r < 32) ? (32 + r) : (64 + r);
        float s = 0.f;
        #pragma unroll
        for (int s8 = 0; s8 < NSTRIP; ++s8)
            s += CS1p[((size_t)(b * NSTRIP + s8) * NCH + ch_c) * PP + q];
        cs_g[r][q] = s;
    }
    for (int k = tid; k < 64 * 128; k += 256) {
        int p = k >> 6, r = k & 63;
        rs_g[r][p] = RS1t[((size_t)b * PP + p) * NCH + 64 + r];
    }
    __syncthreads();
    if (tid < 32) {
        float s = 0.f;
        for (int q = 0; q < 128; ++q) s += cs_g[32 + tid][q];
        s1_96[tid] = s;
    }
    int o = og * 32 + (tid >> 3), qh = tid & 7;
    {
        float wa[64];
        #pragma unroll
        for (int r = 0; r < 64; ++r)
            wa[r] = (r < 32) ? W3[o * NCH + 32 + r] * (1.f / 3.f)
                             : -W3[o * NCH + 64 + r] * (1.f / 9.f);
        #pragma unroll
        for (int j = 0; j < 4; ++j) {
            int q = qh * 16 + j * 4;
            float4 a = {0.f, 0.f, 0.f, 0.f};
            #pragma unroll
            for (int r = 0; r < 64; ++r) {
                float4 cv = *(const float4*)&cs_g[r][q];
                a.x = fmaf(wa[r], cv.x, a.x);
                a.y = fmaf(wa[r], cv.y, a.y);
                a.z = fmaf(wa[r], cv.z, a.z);
                a.w = fmaf(wa[r], cv.w, a.w);
            }
            *(float4*)&Ap[((size_t)b * NCH + o) * PP + q] = a;
        }
    }
    __syncthreads();
    float cc = b3[o];
    #pragma unroll
    for (int r = 0; r < 32; ++r)
        cc = fmaf(W3[o * NCH + 96 + r] * (1.f / 9.f), s1_96[r], cc);
    {
        float wb[64];
        #pragma unroll
        for (int r = 0; r < 64; ++r)
            wb[r] = (r < 32) ? W3[o * NCH + 64 + r] * (1.f / 3.f)
                             : -W3[o * NCH + 64 + r] * (1.f / 9.f);
        #pragma unroll
        for (int j = 0; j < 4; ++j) {
            int p4 = qh * 16 + j * 4;
            float4 a = {0.f, 0.f, 0.f, 0.f};
            #pragma unroll
            for (int r = 0; r < 64; ++r) {
                float4 rv = *(const float4*)&rs_g[r][p4];
                a.x = fmaf(wb[r], rv.x, a.x);
                a.y = fmaf(wb[r], rv.y, a.y);
                a.z = fmaf(wb[r], rv.z, a.z);
                a.w = fmaf(wb[r], rv.w, a.w);
            }
            Bqt[((size_t)b * PP + p4 + 0) * NCH + o] = a.x + cc;
            Bqt[((size_t)b * PP + p4 + 1) * NCH + o] = a.y + cc;
            Bqt[((size_t)b * PP + p4 + 2) * NCH + o] = a.z + cc;
            Bqt[((size_t)b * PP + p4 + 3) * NCH + o] = a.w + cc;
        }
    }
    if (bx == 0) {
        for (int i = 0; i < 16; ++i) {
            int k = tid + i * 256;
            float4 w = *(const float4*)(W3 + k * 4);
            int c0 = (k * 4) & 127;
            float sc = (c0 < 32) ? 1.f : ((c0 < 96) ? (-1.f / 3.f) : (1.f / 9.f));
            unsigned int lo = pk2(w.x * sc, w.y * sc);
            unsigned int hi = pk2(w.z * sc, w.w * sc);
            uint2 u = {lo, hi};
            *(uint2*)(W3bf + k * 4) = u;
        }
    }
}

// ---------------------------------------------------------------------------
// K2: R6 structure + in-pass v sums.  Grid 32 b x 16 strips, 512 threads.
// Per row: t-GEMM1 -> GEMM2 (all 8 nt) -> relu -> pack to v_l -> coalesced
// v2 store (ALL 128 ch, bf16).  Sums: RSvT[b][p][o-64] via shfl+LDS reduce;
// CSp[b][strip][jc][q] register-accumulated (o 32..63 -> jc 0..31,
// o 96..127 -> jc 32..63).  NO scattered global stores anywhere.
// ---------------------------------------------------------------------------
__global__ __launch_bounds__(512, 4) void k2_mfma(const float* __restrict__ phi,
        const float* __restrict__ W1, const float* __restrict__ b1,
        const unsigned short* __restrict__ W3bf,
        const float* __restrict__ Ap, const float* __restrict__ Bqt,
        unsigned short* __restrict__ v2, float* __restrict__ RSvT,
        float* __restrict__ CSp) {
    int bx = blockIdx.x;
    int b = bx >> 4, strip = bx & 15;
    int p0 = strip * 8;
    __shared__ unsigned short w3_l[16384];
    __shared__ unsigned short t_l[16384];
    __shared__ unsigned short phi_b[2][1024];
    __shared__ float BC_l[2][128];
    __shared__ float rs_part[8][64];
    int tid = threadIdx.x;
    int wv = tid >> 6, l = tid & 63, lr = l & 15, lg = l >> 4;
    int q0 = wv * 16 + lg * 4;

    #pragma unroll
    for (int i = 0; i < 4; ++i) {
        int k = tid + i * 512;
        int o = k >> 4, cb = (k & 15) * 16;
        bf16x8 v = *(const bf16x8*)(W3bf + k * 8);
        *(bf16x8*)((char*)w3_l + SWZB(o, cb)) = v;
    }
    bf16x8 w1fr = {0, 0, 0, 0, 0, 0, 0, 0};
    if (lg == 0) {
        int cc = wv * 16 + lr;
        float4 wa = *(const float4*)(W1 + cc * 8);
        float4 wb = *(const float4*)(W1 + cc * 8 + 4);
        w1fr[0] = (short)f2bf(wa.x); w1fr[1] = (short)f2bf(wa.y);
        w1fr[2] = (short)f2bf(wa.z); w1fr[3] = (short)f2bf(wa.w);
        w1fr[4] = (short)f2bf(wb.x); w1fr[5] = (short)f2bf(wb.y);
        w1fr[6] = (short)f2bf(wb.z); w1fr[7] = (short)f2bf(wb.w);
    }
    int c0 = wv * 16 + lg * 4;
    f32x4 binit = {b1[c0], b1[c0 + 1], b1[c0 + 2], b1[c0 + 3]};
    if (tid < 128) {
        bf16x8 pv;
        #pragma unroll
        for (int ci = 0; ci < 8; ++ci)
            pv[ci] = (short)f2bf(phi[((size_t)(b * CIN + ci) * PP + p0) * PP + tid]);
        *(bf16x8*)(phi_b[0] + tid * 8) = pv;
        BC_l[0][tid] = Bqt[((size_t)b * PP + p0) * NCH + tid];
    }
    __syncthreads();

    f32x4 cs_acc[4];
    #pragma unroll
    for (int i = 0; i < 4; ++i) { f32x4 z = {0.f, 0.f, 0.f, 0.f}; cs_acc[i] = z; }

    for (int r = 0; r < 8; ++r) {
        int cur = r & 1, nxt = cur ^ 1;
        int p = p0 + r;
        float pfv[8]; float bcn = 0.f;
        if (r < 7 && tid < 128) {
            #pragma unroll
            for (int ci = 0; ci < 8; ++ci)
                pfv[ci] = phi[((size_t)(b * CIN + ci) * PP + p + 1) * PP + tid];
            bcn = Bqt[((size_t)b * PP + p + 1) * NCH + tid];
        }
        // GEMM1 -> t_l
        const unsigned short* pb = phi_b[cur];
        #pragma unroll
        for (int pt = 0; pt < 8; ++pt) {
            int pix = pt * 16 + lr;
            bf16x8 bfr1 = {0, 0, 0, 0, 0, 0, 0, 0};
            if (lg == 0) bfr1 = *(const bf16x8*)(pb + pix * 8);
            f32x4 a = __builtin_amdgcn_mfma_f32_16x16x32_bf16(w1fr, bfr1, binit, 0, 0, 0);
            uint2 u;
            u.x = pk2(fmaxf(a.x, 0.f), fmaxf(a.y, 0.f));
            u.y = pk2(fmaxf(a.z, 0.f), fmaxf(a.w, 0.f));
            *(uint2*)((char*)t_l + SWZB(pix, c0 * 2)) = u;
        }
        __syncthreads();                     // (A) t_l ready
        bf16x8 afr[4];
        #pragma unroll
        for (int ks = 0; ks < 4; ++ks)
            afr[ks] = *(const bf16x8*)((char*)t_l + SWZB(wv * 16 + lr, ks * 64 + lg * 16));
        uint2 vpk[8];
        #pragma unroll
        for (int nt = 0; nt < 8; ++nt) {
            int o = nt * 16 + lr;
            bf16x8 bfr[4];
            #pragma unroll
            for (int ks = 0; ks < 4; ++ks)
                bfr[ks] = *(const bf16x8*)((char*)w3_l + SWZB(o, ks * 64 + lg * 16));
            f32x4 ap = *(const f32x4*)(Ap + ((size_t)(b * NCH + o)) * PP + q0);
            f32x4 acc = ap + BC_l[cur][o];
            #pragma unroll
            for (int ks = 0; ks < 4; ++ks)
                acc = __builtin_amdgcn_mfma_f32_16x16x32_bf16(afr[ks], bfr[ks], acc, 0, 0, 0);
            f32x4 v = {fmaxf(acc.x, 0.f), fmaxf(acc.y, 0.f), fmaxf(acc.z, 0.f), fmaxf(acc.w, 0.f)};
            if (nt == 2 || nt == 3) cs_acc[nt - 2] += v;
            else if (nt >= 6)       cs_acc[nt - 4] += v;
            if (nt >= 4) {
                float rsv = v.x + v.y + v.z + v.w;
                rsv += __shfl_xor(rsv, 16);
                rsv += __shfl_xor(rsv, 32);
                if (lg == 0) rs_part[wv][(nt - 4) * 16 + lr] = rsv;
            }
            vpk[nt].x = pk2(v.x, v.y);
            vpk[nt].y = pk2(v.z, v.w);
        }
        __syncthreads();                     // (B) afr reads done -> t_l reusable
        #pragma unroll
        for (int nt = 0; nt < 8; ++nt) {
            int o = nt * 16 + lr;
            *(uint2*)((char*)t_l + SWZB(o, q0 * 2)) = vpk[nt];
        }
        if (r < 7 && tid < 128) {
            bf16x8 pv;
            #pragma unroll
            for (int ci = 0; ci < 8; ++ci) pv[ci] = (short)f2bf(pfv[ci]);
            *(bf16x8*)(phi_b[nxt] + tid * 8) = pv;
            BC_l[nxt][tid] = bcn;
        }
        __syncthreads();                     // (C) v_l + next phi ready
        #pragma unroll
        for (int i = 0; i < 4; ++i) {
            int k = tid + i * 512;           // 2048 chunks = 128 ch x 16
            int o = k >> 4, j = k & 15;
            bf16x8 v = *(const bf16x8*)((char*)t_l + SWZB(o, j * 16));
            *(bf16x8*)(v2 + ((size_t)(b * NCH + o) * PP + p) * PP + j * 8) = v;
        }
        if (tid < 64) {
            float s = 0.f;
            #pragma unroll
            for (int w8 = 0; w8 < 8; ++w8) s += rs_part[w8][tid];
            RSvT[((size_t)(b * PP + p)) * 64 + tid] = s;
        }
        __syncthreads();                     // (D) v_l reads done before next GEMM1
    }
    // store cs strip-partials (jc: nt2->lr, nt3->16+lr, nt6->32+lr, nt7->48+lr)
    {
        float* dst = CSp + ((size_t)(b * KSTRIP + strip)) * 64 * PP;
        *(f32x4*)(dst + (size_t)(lr)      * PP + q0) = cs_acc[0];
        *(f32x4*)(dst + (size_t)(16 + lr) * PP + q0) = cs_acc[1];
        *(f32x4*)(dst + (size_t)(32 + lr) * PP + q0) = cs_acc[2];
        *(f32x4*)(dst + (size_t)(48 + lr) * PP + q0) = cs_acc[3];
    }
}

// ---------------------------------------------------------------------------
// K2s: CSv[b][jc][q] = sum_strip CSp; Sb[b][jo] = sum_p RSvT[b][p][32+jo].
// ---------------------------------------------------------------------------
__global__ __launch_bounds__(256) void k2s_reduce(const float* __restrict__ CSp,
        const float* __restrict__ RSvT, float* __restrict__ CSv,
        float* __restrict__ Sb) {
    int b = blockIdx.x, tid = threadIdx.x;
    for (int k = tid; k < 64 * PP; k += 256) {
        float s = 0.f;
        #pragma unroll
        for (int st = 0; st < KSTRIP; ++st)
            s += CSp[((size_t)(b * KSTRIP + st)) * 64 * PP + k];
        CSv[(size_t)b * 64 * PP + k] = s;
    }
    if (tid < 32) {
        float s = 0.f;
        for (int p = 0; p < PP; ++p) s += RSvT[((size_t)(b * PP + p)) * 64 + 32 + tid];
        Sb[b * 32 + tid] = s;
    }
}

// ---------------------------------------------------------------------------
// K3: single-pass postprocess, all 128 ch.  One block per (b,ch); fully
// coalesced read (bf16 plane) and write (f32 plane).
// ---------------------------------------------------------------------------
__global__ __launch_bounds__(256) void k3_out(const unsigned short* __restrict__ v2,
        const float* __restrict__ RSvT, const float* __restrict__ CSv,
        const float* __restrict__ Sb, float* __restrict__ out) {
    int bx = blockIdx.x;
    int b = bx >> 7, ch = bx & 127;
    int g = ch >> 5;
    __shared__ float rs_l[128], cs_l[128];
    int tid = threadIdx.x;
    size_t base = (size_t)(b * NCH + ch) * (PP * PP);
    const unsigned short* src = v2 + base;
    float* dst = out + base;
    if (tid < 128) {
        if (g >= 2) rs_l[tid] = RSvT[((size_t)(b * PP) + tid) * 64 + (ch - 64)];
        if (g == 1) cs_l[tid] = CSv[((size_t)b * 64 + (ch - 32)) * PP + tid];
        if (g == 3) cs_l[tid] = CSv[((size_t)b * 64 + (ch - 64)) * PP + tid];
    }
    float stot = (g == 3) ? Sb[b * 32 + (ch - 96)] : 0.f;
    __syncthreads();
    #pragma unroll
    for (int i = 0; i < 8; ++i) {
        int k = tid + i * 256;
        int pr = k >> 4, q0 = (k & 15) * 8;
        bf16x8 u = *(const bf16x8*)(src + pr * PP + q0);
        float rp = (g >= 2) ? rs_l[pr] : 0.f;
        float o8[8];
        #pragma unroll
        for (int e = 0; e < 8; ++e) {
            float v = bf2f((unsigned short)u[e]);
            float r;
            if (g == 0)      r = v;
            else if (g == 1) r = (cs_l[q0 + e] - v) * (1.f / 3.f);
            else if (g == 2) r = (rp - v) * (1.f / 3.f);
            else             r = ((stot - rp) - cs_l[q0 + e] + v) * (1.f / 9.f);
            o8[e] = r;
        }
        f32x4 lo = {o8[0], o8[1], o8[2], o8[3]};
        f32x4 hi = {o8[4], o8[5], o8[6], o8[7]};
        *(f32x4*)(dst + pr * PP + q0)     = lo;
        *(f32x4*)(dst + pr * PP + q0 + 4) = hi;
    }
}

// ---------------------------------------------------------------------------
extern "C" void kernel_launch(void* const* d_in, const int* in_sizes, int n_in,
                              void* d_out, int out_size, void* d_ws, size_t ws_size,
                              hipStream_t stream) {
    (void)in_sizes; (void)n_in; (void)out_size; (void)ws_size;
    const float* phi = (const float*)d_in[0];
    const float* W1  = (const float*)d_in[1];
    const float* b1  = (const float*)d_in[2];
    const float* W3  = (const float*)d_in[3];
    const float* b3  = (const float*)d_in[4];
    float* out = (float*)d_out;

    char* ws = (char*)d_ws;
    size_t off = 0;
    unsigned short* v2 = (unsigned short*)(ws + off); off += (size_t)BATCH * NCH * PP * PP * 2; // 134 MB
    float* RS1t = (float*)(ws + off); off += (size_t)BATCH * NCH * PP * 4;            // 2 MB
    float* CS1p = (float*)(ws + off); off += (size_t)BATCH * NSTRIP * NCH * PP * 4;   // 16 MB
    float* Ap   = (float*)(ws + off); off += (size_t)BATCH * NCH * PP * 4;            // 8 MB
    float* Bqt  = (float*)(ws + off); off += (size_t)BATCH * NCH * PP * 4;            // 8 MB
    unsigned short* W3bf = (unsigned short*)(ws + off); off += (size_t)NCH * NCH * 2; // 32 KB
    float* RSvT = (float*)(ws + off); off += (size_t)BATCH * PP * 64 * 4;             // 1 MB
    float* CSp  = (float*)(ws + off); off += (size_t)BATCH * KSTRIP * 64 * PP * 4;    // 16 MB
    float* CSv  = (float*)(ws + off); off += (size_t)BATCH * 64 * PP * 4;             // 1 MB
    float* Sb   = (float*)(ws + off); off += (size_t)BATCH * 32 * 4;                  // 4 KB

    k1_sums<<<BATCH * NSTRIP, 512, 0, stream>>>(phi, W1, b1, RS1t, CS1p);
    k1b_planes<<<BATCH * 4, 256, 0, stream>>>(W3, b3, RS1t, CS1p, Ap, Bqt, W3bf);
    k2_mfma<<<BATCH * KSTRIP, 512, 0, stream>>>(phi, W1, b1, W3bf, Ap, Bqt, v2, RSvT, CSp);
    k2s_reduce<<<BATCH, 256, 0, stream>>>(CSp, RSvT, CSv, Sb);
    k3_out<<<BATCH * NCH, 256, 0, stream>>>(v2, RSvT, CSv, Sb, out);
}

// Round 9
// 201.275 us; speedup vs baseline: 1.6472x; 1.5886x over previous
//
#include <hip/hip_runtime.h>
#include <stdint.h>

#define BATCH 32
#define CIN   8
#define NCH   128   // 4*F_DIM
#define PP    128   // P
#define NSTRIP 8    // k1 strips per batch (16 p each)
#define KSTRIP 16   // k2 strips per batch (8 p each)

typedef __attribute__((ext_vector_type(8))) short    bf16x8;
typedef __attribute__((ext_vector_type(4))) float    f32x4;

__device__ __forceinline__ float bf2f(unsigned short u) {
    union { unsigned int i; float f; } x; x.i = ((unsigned int)u) << 16; return x.f;
}
__device__ __forceinline__ unsigned short f2bf(float f) {
    union { float f; unsigned int i; } x; x.f = f;
    unsigned int r = x.i + 0x7fffu + ((x.i >> 16) & 1u);
    return (unsigned short)(r >> 16);
}
__device__ __forceinline__ unsigned int pk2(float a, float b) {
    return (unsigned int)f2bf(a) | ((unsigned int)f2bf(b) << 16);
}

// Swizzled byte offset into a [128 rows][128 bf16] LDS tile (row = 256 B).
#define SWZB(row, cb) (((row) << 8) + ((cb) ^ (((row) & 7) << 4)))

// ---------------------------------------------------------------------------
// K1: RS1t[b][p][c] = sum_q t ; CS1p[b][strip][c][q] = partial sum_p t.
// ---------------------------------------------------------------------------
__global__ __launch_bounds__(512) void k1_sums(const float* __restrict__ phi,
        const float* __restrict__ W1, const float* __restrict__ b1,
        float* __restrict__ RS1t, float* __restrict__ CS1p) {
    __shared__ float S[17408];
    int bx = blockIdx.x;
    int b = bx >> 3, strip = bx & 7;
    int p0 = strip * 16;
    int tid = threadIdx.x;
    int c = tid & 127, qq = tid >> 7;

    #pragma unroll
    for (int i = 0; i < 8; ++i) {
        int idx = tid + i * 512;                 // float4 index
        int pi = idx >> 8, ci = (idx >> 5) & 7, q4 = (idx & 31) * 4;
        float4 v = *(const float4*)(phi + ((size_t)(b * CIN + ci) * PP + p0 + pi) * PP + q4);
        *(float4*)(S + pi * 1024 + ci * 128 + q4) = v;
    }
    float4 w1a = *(const float4*)(W1 + c * 8);
    float4 w1b = *(const float4*)(W1 + c * 8 + 4);
    float b1c = b1[c];
    float cs_acc[32];
    #pragma unroll
    for (int j = 0; j < 32; ++j) cs_acc[j] = 0.f;
    float rsp[16];
    __syncthreads();

    for (int pi = 0; pi < 16; ++pi) {
        float rs = 0.f;
        const float* pb = S + pi * 1024;
        #pragma unroll
        for (int j4 = 0; j4 < 8; ++j4) {
            int q4 = qq * 32 + j4 * 4;
            float4 ph[8];
            #pragma unroll
            for (int ci = 0; ci < 8; ++ci)
                ph[ci] = *(const float4*)(pb + ci * 128 + q4);
            #pragma unroll
            for (int e = 0; e < 4; ++e) {
                float t = b1c;
                t = fmaf(w1a.x, ((const float*)&ph[0])[e], t);
                t = fmaf(w1a.y, ((const float*)&ph[1])[e], t);
                t = fmaf(w1a.z, ((const float*)&ph[2])[e], t);
                t = fmaf(w1a.w, ((const float*)&ph[3])[e], t);
                t = fmaf(w1b.x, ((const float*)&ph[4])[e], t);
                t = fmaf(w1b.y, ((const float*)&ph[5])[e], t);
                t = fmaf(w1b.z, ((const float*)&ph[6])[e], t);
                t = fmaf(w1b.w, ((const float*)&ph[7])[e], t);
                t = fmaxf(t, 0.f);
                cs_acc[j4 * 4 + e] += t;
                rs += t;
            }
        }
        rsp[pi] = rs;
    }
    __syncthreads();
    #pragma unroll
    for (int pi = 0; pi < 16; ++pi) S[pi * 512 + tid] = rsp[pi];
    __syncthreads();
    #pragma unroll
    for (int i = 0; i < 4; ++i) {
        int idx = tid + i * 512;
        int pi = idx >> 7, cc = idx & 127;
        float s = S[pi * 512 + cc] + S[pi * 512 + 128 + cc]
                + S[pi * 512 + 256 + cc] + S[pi * 512 + 384 + cc];
        RS1t[((size_t)b * PP + p0 + pi) * NCH + cc] = s;
    }
    __syncthreads();
    #pragma unroll
    for (int j4 = 0; j4 < 8; ++j4) {
        float4 v = {cs_acc[j4 * 4], cs_acc[j4 * 4 + 1], cs_acc[j4 * 4 + 2], cs_acc[j4 * 4 + 3]};
        *(float4*)(S + c * 132 + qq * 32 + j4 * 4) = v;
    }
    __syncthreads();
    float* dstp = CS1p + (size_t)(b * NSTRIP + strip) * NCH * PP;
    for (int k = tid; k < 16384; k += 512) {
        int cc = k >> 7, q = k & 127;
        dstp[k] = S[cc * 132 + q];
    }
}

// ---------------------------------------------------------------------------
// K1b: Ap[b][o][q], Bqt[b][p][o] (with Cc folded in), W3bf (block 0).
// ---------------------------------------------------------------------------
__global__ __launch_bounds__(256) void k1b_planes(const float* __restrict__ W3,
        const float* __restrict__ b3, const float* __restrict__ RS1t,
        const float* __restrict__ CS1p, float* __restrict__ Ap,
        float* __restrict__ Bqt, unsigned short* __restrict__ W3bf) {
    int bx = blockIdx.x;
    int b = bx >> 2, og = bx & 3;
    int tid = threadIdx.x;
    __shared__ float cs_g[64][132];
    __shared__ float rs_g[64][132];
    __shared__ float s1_96[32];
    for (int k = tid; k < 64 * 128; k += 256) {
        int r = k >> 7, q = k & 127;
        int ch_c = (r < 32) ? (32 + r) : (64 + r);
        float s = 0.f;
        #pragma unroll
        for (int s8 = 0; s8 < NSTRIP; ++s8)
            s += CS1p[((size_t)(b * NSTRIP + s8) * NCH + ch_c) * PP + q];
        cs_g[r][q] = s;
    }
    for (int k = tid; k < 64 * 128; k += 256) {
        int p = k >> 6, r = k & 63;
        rs_g[r][p] = RS1t[((size_t)b * PP + p) * NCH + 64 + r];
    }
    __syncthreads();
    if (tid < 32) {
        float s = 0.f;
        for (int q = 0; q < 128; ++q) s += cs_g[32 + tid][q];
        s1_96[tid] = s;
    }
    int o = og * 32 + (tid >> 3), qh = tid & 7;
    {
        float wa[64];
        #pragma unroll
        for (int r = 0; r < 64; ++r)
            wa[r] = (r < 32) ? W3[o * NCH + 32 + r] * (1.f / 3.f)
                             : -W3[o * NCH + 64 + r] * (1.f / 9.f);
        #pragma unroll
        for (int j = 0; j < 4; ++j) {
            int q = qh * 16 + j * 4;
            float4 a = {0.f, 0.f, 0.f, 0.f};
            #pragma unroll
            for (int r = 0; r < 64; ++r) {
                float4 cv = *(const float4*)&cs_g[r][q];
                a.x = fmaf(wa[r], cv.x, a.x);
                a.y = fmaf(wa[r], cv.y, a.y);
                a.z = fmaf(wa[r], cv.z, a.z);
                a.w = fmaf(wa[r], cv.w, a.w);
            }
            *(float4*)&Ap[((size_t)b * NCH + o) * PP + q] = a;
        }
    }
    __syncthreads();
    float cc = b3[o];
    #pragma unroll
    for (int r = 0; r < 32; ++r)
        cc = fmaf(W3[o * NCH + 96 + r] * (1.f / 9.f), s1_96[r], cc);
    {
        float wb[64];
        #pragma unroll
        for (int r = 0; r < 64; ++r)
            wb[r] = (r < 32) ? W3[o * NCH + 64 + r] * (1.f / 3.f)
                             : -W3[o * NCH + 64 + r] * (1.f / 9.f);
        #pragma unroll
        for (int j = 0; j < 4; ++j) {
            int p4 = qh * 16 + j * 4;
            float4 a = {0.f, 0.f, 0.f, 0.f};
            #pragma unroll
            for (int r = 0; r < 64; ++r) {
                float4 rv = *(const float4*)&rs_g[r][p4];
                a.x = fmaf(wb[r], rv.x, a.x);
                a.y = fmaf(wb[r], rv.y, a.y);
                a.z = fmaf(wb[r], rv.z, a.z);
                a.w = fmaf(wb[r], rv.w, a.w);
            }
            Bqt[((size_t)b * PP + p4 + 0) * NCH + o] = a.x + cc;
            Bqt[((size_t)b * PP + p4 + 1) * NCH + o] = a.y + cc;
            Bqt[((size_t)b * PP + p4 + 2) * NCH + o] = a.z + cc;
            Bqt[((size_t)b * PP + p4 + 3) * NCH + o] = a.w + cc;
        }
    }
    if (bx == 0) {
        for (int i = 0; i < 16; ++i) {
            int k = tid + i * 256;
            float4 w = *(const float4*)(W3 + k * 4);
            int c0 = (k * 4) & 127;
            float sc = (c0 < 32) ? 1.f : ((c0 < 96) ? (-1.f / 3.f) : (1.f / 9.f));
            unsigned int lo = pk2(w.x * sc, w.y * sc);
            unsigned int hi = pk2(w.z * sc, w.w * sc);
            uint2 u = {lo, hi};
            *(uint2*)(W3bf + k * 4) = u;
        }
    }
}

// ---------------------------------------------------------------------------
// K2: SLIM MFMA kernel (no sums, no vpk, Ap hoisted to registers).
// Grid 32 b x 16 strips, 512 threads.  Per row: GEMM1 -> (A) -> afr -> (B)
// -> GEMM2 writes relu'd v directly into t_l -> (C) -> coalesced v2 store
// -> (D).  All 128 channels to v2 bf16.
// ---------------------------------------------------------------------------
__global__ __launch_bounds__(512, 4) void k2_mfma(const float* __restrict__ phi,
        const float* __restrict__ W1, const float* __restrict__ b1,
        const unsigned short* __restrict__ W3bf,
        const float* __restrict__ Ap, const float* __restrict__ Bqt,
        unsigned short* __restrict__ v2) {
    int bx = blockIdx.x;
    int b = bx >> 4, strip = bx & 15;
    int p0 = strip * 8;
    __shared__ unsigned short w3_l[16384];
    __shared__ unsigned short t_l[16384];
    __shared__ unsigned short phi_b[2][1024];
    __shared__ float BC_l[2][128];
    int tid = threadIdx.x;
    int wv = tid >> 6, l = tid & 63, lr = l & 15, lg = l >> 4;
    int q0 = wv * 16 + lg * 4;

    #pragma unroll
    for (int i = 0; i < 4; ++i) {
        int k = tid + i * 512;
        int o = k >> 4, cb = (k & 15) * 16;
        bf16x8 v = *(const bf16x8*)(W3bf + k * 8);
        *(bf16x8*)((char*)w3_l + SWZB(o, cb)) = v;
    }
    bf16x8 w1fr = {0, 0, 0, 0, 0, 0, 0, 0};
    if (lg == 0) {
        int cc = wv * 16 + lr;
        float4 wa = *(const float4*)(W1 + cc * 8);
        float4 wb = *(const float4*)(W1 + cc * 8 + 4);
        w1fr[0] = (short)f2bf(wa.x); w1fr[1] = (short)f2bf(wa.y);
        w1fr[2] = (short)f2bf(wa.z); w1fr[3] = (short)f2bf(wa.w);
        w1fr[4] = (short)f2bf(wb.x); w1fr[5] = (short)f2bf(wb.y);
        w1fr[6] = (short)f2bf(wb.z); w1fr[7] = (short)f2bf(wb.w);
    }
    int c0 = wv * 16 + lg * 4;
    f32x4 binit = {b1[c0], b1[c0 + 1], b1[c0 + 2], b1[c0 + 3]};
    // Ap hoisted: one f32x4 per nt, loaded ONCE per block (coalesced per o-row)
    f32x4 apr[8];
    #pragma unroll
    for (int nt = 0; nt < 8; ++nt)
        apr[nt] = *(const f32x4*)(Ap + ((size_t)(b * NCH + nt * 16 + lr)) * PP + q0);
    if (tid < 128) {
        bf16x8 pv;
        #pragma unroll
        for (int ci = 0; ci < 8; ++ci)
            pv[ci] = (short)f2bf(phi[((size_t)(b * CIN + ci) * PP + p0) * PP + tid]);
        *(bf16x8*)(phi_b[0] + tid * 8) = pv;
        BC_l[0][tid] = Bqt[((size_t)b * PP + p0) * NCH + tid];
    }
    __syncthreads();

    for (int r = 0; r < 8; ++r) {
        int cur = r & 1, nxt = cur ^ 1;
        int p = p0 + r;
        float pfv[8]; float bcn = 0.f;
        if (r < 7 && tid < 128) {
            #pragma unroll
            for (int ci = 0; ci < 8; ++ci)
                pfv[ci] = phi[((size_t)(b * CIN + ci) * PP + p + 1) * PP + tid];
            bcn = Bqt[((size_t)b * PP + p + 1) * NCH + tid];
        }
        // GEMM1 -> t_l
        const unsigned short* pb = phi_b[cur];
        #pragma unroll
        for (int pt = 0; pt < 8; ++pt) {
            int pix = pt * 16 + lr;
            bf16x8 bfr1 = {0, 0, 0, 0, 0, 0, 0, 0};
            if (lg == 0) bfr1 = *(const bf16x8*)(pb + pix * 8);
            f32x4 a = __builtin_amdgcn_mfma_f32_16x16x32_bf16(w1fr, bfr1, binit, 0, 0, 0);
            uint2 u;
            u.x = pk2(fmaxf(a.x, 0.f), fmaxf(a.y, 0.f));
            u.y = pk2(fmaxf(a.z, 0.f), fmaxf(a.w, 0.f));
            *(uint2*)((char*)t_l + SWZB(pix, c0 * 2)) = u;
        }
        __syncthreads();                     // (A) t_l ready
        bf16x8 afr[4];
        #pragma unroll
        for (int ks = 0; ks < 4; ++ks)
            afr[ks] = *(const bf16x8*)((char*)t_l + SWZB(wv * 16 + lr, ks * 64 + lg * 16));
        __syncthreads();                     // (B) all afr reads done -> t_l reusable
        #pragma unroll
        for (int nt = 0; nt < 8; ++nt) {
            int o = nt * 16 + lr;
            bf16x8 bfr[4];
            #pragma unroll
            for (int ks = 0; ks < 4; ++ks)
                bfr[ks] = *(const bf16x8*)((char*)w3_l + SWZB(o, ks * 64 + lg * 16));
            f32x4 acc = apr[nt] + BC_l[cur][o];
            #pragma unroll
            for (int ks = 0; ks < 4; ++ks)
                acc = __builtin_amdgcn_mfma_f32_16x16x32_bf16(afr[ks], bfr[ks], acc, 0, 0, 0);
            uint2 u;
            u.x = pk2(fmaxf(acc.x, 0.f), fmaxf(acc.y, 0.f));
            u.y = pk2(fmaxf(acc.z, 0.f), fmaxf(acc.w, 0.f));
            *(uint2*)((char*)t_l + SWZB(o, q0 * 2)) = u;
        }
        if (r < 7 && tid < 128) {
            bf16x8 pv;
            #pragma unroll
            for (int ci = 0; ci < 8; ++ci) pv[ci] = (short)f2bf(pfv[ci]);
            *(bf16x8*)(phi_b[nxt] + tid * 8) = pv;
            BC_l[nxt][tid] = bcn;
        }
        __syncthreads();                     // (C) v_l complete + next phi ready
        #pragma unroll
        for (int i = 0; i < 4; ++i) {
            int k = tid + i * 512;           // 2048 chunks = 128 ch x 16
            int o = k >> 4, j = k & 15;
            bf16x8 v = *(const bf16x8*)((char*)t_l + SWZB(o, j * 16));
            *(bf16x8*)(v2 + ((size_t)(b * NCH + o) * PP + p) * PP + j * 8) = v;
        }
        __syncthreads();                     // (D) v_l reads done before next GEMM1
    }
}

// ---------------------------------------------------------------------------
// K3: self-contained sums + postprocess.  One block per (b,ch); stages the
// bf16 plane in LDS once, computes rs/cs/S locally, writes f32 out coalesced.
// ---------------------------------------------------------------------------
__global__ __launch_bounds__(256) void k3_out(const unsigned short* __restrict__ v2,
        float* __restrict__ out) {
    int bx = blockIdx.x;
    int b = bx >> 7, ch = bx & 127;
    int g = ch >> 5;
    __shared__ unsigned short v_l[128 * 136];
    __shared__ float rs_l[128], cs_l[128];
    __shared__ float s_sh;
    int tid = threadIdx.x;
    size_t base = (size_t)(b * NCH + ch) * (PP * PP);
    const unsigned short* src = v2 + base;
    #pragma unroll
    for (int i = 0; i < 8; ++i) {
        int k = tid + i * 256;
        int pr = k >> 4, c8 = k & 15;
        *(bf16x8*)(v_l + pr * 136 + c8 * 8) = *(const bf16x8*)(src + k * 8);
    }
    __syncthreads();
    if (tid < 128) {
        float s = 0.f;
        #pragma unroll 4
        for (int j = 0; j < 16; ++j) {
            bf16x8 u = *(const bf16x8*)(v_l + tid * 136 + j * 8);
            #pragma unroll
            for (int e = 0; e < 8; ++e) s += bf2f((unsigned short)u[e]);
        }
        rs_l[tid] = s;
    } else {
        int q = tid - 128;
        float s = 0.f;
        for (int pr = 0; pr < 128; ++pr) s += bf2f(v_l[pr * 136 + q]);
        cs_l[q] = s;
    }
    __syncthreads();
    if (tid < 64) {
        float s = rs_l[tid] + rs_l[tid + 64];
        #pragma unroll
        for (int off = 32; off > 0; off >>= 1) s += __shfl_down(s, off);
        if (tid == 0) s_sh = s;
    }
    __syncthreads();
    float stot = s_sh;
    float* dst = out + base;
    #pragma unroll
    for (int i = 0; i < 8; ++i) {
        int k = tid + i * 256;
        int pr = k >> 4, q0 = (k & 15) * 8;
        bf16x8 u = *(const bf16x8*)(v_l + pr * 136 + q0);
        float rp = rs_l[pr];
        float o8[8];
        #pragma unroll
        for (int e = 0; e < 8; ++e) {
            float v = bf2f((unsigned short)u[e]);
            float cq = cs_l[q0 + e];
            float r;
            if (g == 0)      r = v;
            else if (g == 1) r = (cq - v) * (1.f / 3.f);
            else if (g == 2) r = (rp - v) * (1.f / 3.f);
            else             r = ((stot - rp) - cq + v) * (1.f / 9.f);
            o8[e] = r;
        }
        f32x4 lo = {o8[0], o8[1], o8[2], o8[3]};
        f32x4 hi = {o8[4], o8[5], o8[6], o8[7]};
        *(f32x4*)(dst + pr * PP + q0)     = lo;
        *(f32x4*)(dst + pr * PP + q0 + 4) = hi;
    }
}

// ---------------------------------------------------------------------------
extern "C" void kernel_launch(void* const* d_in, const int* in_sizes, int n_in,
                              void* d_out, int out_size, void* d_ws, size_t ws_size,
                              hipStream_t stream) {
    (void)in_sizes; (void)n_in; (void)out_size; (void)ws_size;
    const float* phi = (const float*)d_in[0];
    const float* W1  = (const float*)d_in[1];
    const float* b1  = (const float*)d_in[2];
    const float* W3  = (const float*)d_in[3];
    const float* b3  = (const float*)d_in[4];
    float* out = (float*)d_out;

    char* ws = (char*)d_ws;
    size_t off = 0;
    unsigned short* v2 = (unsigned short*)(ws + off); off += (size_t)BATCH * NCH * PP * PP * 2; // 134 MB
    float* RS1t = (float*)(ws + off); off += (size_t)BATCH * NCH * PP * 4;            // 2 MB
    float* CS1p = (float*)(ws + off); off += (size_t)BATCH * NSTRIP * NCH * PP * 4;   // 16 MB
    float* Ap   = (float*)(ws + off); off += (size_t)BATCH * NCH * PP * 4;            // 8 MB
    float* Bqt  = (float*)(ws + off); off += (size_t)BATCH * NCH * PP * 4;            // 8 MB
    unsigned short* W3bf = (unsigned short*)(ws + off); off += (size_t)NCH * NCH * 2; // 32 KB

    k1_sums<<<BATCH * NSTRIP, 512, 0, stream>>>(phi, W1, b1, RS1t, CS1p);
    k1b_planes<<<BATCH * 4, 256, 0, stream>>>(W3, b3, RS1t, CS1p, Ap, Bqt, W3bf);
    k2_mfma<<<BATCH * KSTRIP, 512, 0, stream>>>(phi, W1, b1, W3bf, Ap, Bqt, v2);
    k3_out<<<BATCH * NCH, 256, 0, stream>>>(v2, out);
}

// Round 10
// 198.368 us; speedup vs baseline: 1.6714x; 1.0147x over previous
//
#include <hip/hip_runtime.h>
#include <stdint.h>

#define BATCH 32
#define CIN   8
#define NCH   128   // 4*F_DIM
#define PP    128   // P
#define NSTRIP 8    // k1 strips per batch (16 p each)
#define KSTRIP 16   // k2 strips per batch (8 p each)

typedef __attribute__((ext_vector_type(8))) short    bf16x8;
typedef __attribute__((ext_vector_type(4))) float    f32x4;

__device__ __forceinline__ float bf2f(unsigned short u) {
    union { unsigned int i; float f; } x; x.i = ((unsigned int)u) << 16; return x.f;
}
__device__ __forceinline__ unsigned short f2bf(float f) {
    union { float f; unsigned int i; } x; x.f = f;
    unsigned int r = x.i + 0x7fffu + ((x.i >> 16) & 1u);
    return (unsigned short)(r >> 16);
}
__device__ __forceinline__ unsigned int pk2(float a, float b) {
    return (unsigned int)f2bf(a) | ((unsigned int)f2bf(b) << 16);
}

// Swizzled byte offset into a [128 rows][128 bf16] LDS tile (row = 256 B).
#define SWZB(row, cb) (((row) << 8) + ((cb) ^ (((row) & 7) << 4)))

// ---------------------------------------------------------------------------
// K1 (MFMA version): RS1t[b][p][c] = sum_q t ; CS1p[b][strip][c][q] partial.
// t = relu(W1.phi + b1) via mfma_16x16x32 (K-pad in regs, k2's GEMM1 pattern).
// D-layout: lane (lg,lr) holds c = wv*16+lg*4+e, q = pt*16+lr.
// cs: register accumulation across 16 rows (lane mapping row-invariant).
// rs: f32x4 shfl_xor reduce over lr lanes, f32x4 store by lr==0 lanes.
// One barrier per row.  Grid: 32 b x 8 strips, 512 thr.
// ---------------------------------------------------------------------------
__global__ __launch_bounds__(512, 4) void k1_sums(const float* __restrict__ phi,
        const float* __restrict__ W1, const float* __restrict__ b1,
        float* __restrict__ RS1t, float* __restrict__ CS1p) {
    __shared__ float cs_f[128 * 132];           // 67.6 KB, live only at flush
    __shared__ unsigned short phi_b[2][1024];   // [q][ci] bf16
    int bx = blockIdx.x;
    int b = bx >> 3, strip = bx & 7;
    int p0 = strip * 16;
    int tid = threadIdx.x;
    int wv = tid >> 6, l = tid & 63, lr = l & 15, lg = l >> 4;
    int c0 = wv * 16 + lg * 4;

    bf16x8 w1fr = {0, 0, 0, 0, 0, 0, 0, 0};
    if (lg == 0) {
        int cc = wv * 16 + lr;
        float4 wa = *(const float4*)(W1 + cc * 8);
        float4 wb = *(const float4*)(W1 + cc * 8 + 4);
        w1fr[0] = (short)f2bf(wa.x); w1fr[1] = (short)f2bf(wa.y);
        w1fr[2] = (short)f2bf(wa.z); w1fr[3] = (short)f2bf(wa.w);
        w1fr[4] = (short)f2bf(wb.x); w1fr[5] = (short)f2bf(wb.y);
        w1fr[6] = (short)f2bf(wb.z); w1fr[7] = (short)f2bf(wb.w);
    }
    f32x4 binit = {b1[c0], b1[c0 + 1], b1[c0 + 2], b1[c0 + 3]};
    if (tid < 128) {
        bf16x8 pv;
        #pragma unroll
        for (int ci = 0; ci < 8; ++ci)
            pv[ci] = (short)f2bf(phi[((size_t)(b * CIN + ci) * PP + p0) * PP + tid]);
        *(bf16x8*)(phi_b[0] + tid * 8) = pv;
    }
    __syncthreads();

    f32x4 cs_acc[8];
    #pragma unroll
    for (int i = 0; i < 8; ++i) { f32x4 z = {0.f, 0.f, 0.f, 0.f}; cs_acc[i] = z; }

    int cur = 0;
    for (int r = 0; r < 16; ++r) {
        int p = p0 + r;
        float pfv[8];
        if (r < 15 && tid < 128) {
            #pragma unroll
            for (int ci = 0; ci < 8; ++ci)
                pfv[ci] = phi[((size_t)(b * CIN + ci) * PP + p + 1) * PP + tid];
        }
        const unsigned short* pb = phi_b[cur];
        f32x4 rs4 = {0.f, 0.f, 0.f, 0.f};
        #pragma unroll
        for (int pt = 0; pt < 8; ++pt) {
            int pix = pt * 16 + lr;
            bf16x8 bfr1 = {0, 0, 0, 0, 0, 0, 0, 0};
            if (lg == 0) bfr1 = *(const bf16x8*)(pb + pix * 8);
            f32x4 a = __builtin_amdgcn_mfma_f32_16x16x32_bf16(w1fr, bfr1, binit, 0, 0, 0);
            f32x4 v = {fmaxf(a.x, 0.f), fmaxf(a.y, 0.f), fmaxf(a.z, 0.f), fmaxf(a.w, 0.f)};
            cs_acc[pt] += v;
            rs4 += v;
        }
        // reduce rs4 across the 16 lr lanes (c is lr-invariant)
        #pragma unroll
        for (int m = 1; m < 16; m <<= 1) {
            rs4.x += __shfl_xor(rs4.x, m);
            rs4.y += __shfl_xor(rs4.y, m);
            rs4.z += __shfl_xor(rs4.z, m);
            rs4.w += __shfl_xor(rs4.w, m);
        }
        if (lr == 0)
            *(f32x4*)(RS1t + ((size_t)b * PP + p) * NCH + c0) = rs4;
        if (r < 15 && tid < 128) {
            bf16x8 pv;
            #pragma unroll
            for (int ci = 0; ci < 8; ++ci) pv[ci] = (short)f2bf(pfv[ci]);
            *(bf16x8*)(phi_b[cur ^ 1] + tid * 8) = pv;
        }
        __syncthreads();
        cur ^= 1;
    }
    // flush register col-sums -> LDS -> coalesced CS1p store
    #pragma unroll
    for (int pt = 0; pt < 8; ++pt) {
        f32x4 v = cs_acc[pt];
        int q = pt * 16 + lr;
        cs_f[(c0 + 0) * 132 + q] = v.x;
        cs_f[(c0 + 1) * 132 + q] = v.y;
        cs_f[(c0 + 2) * 132 + q] = v.z;
        cs_f[(c0 + 3) * 132 + q] = v.w;
    }
    __syncthreads();
    float* dstp = CS1p + (size_t)(b * NSTRIP + strip) * NCH * PP;
    for (int k = tid; k < 16384; k += 512) {
        int cc = k >> 7, q = k & 127;
        dstp[k] = cs_f[cc * 132 + q];
    }
}

// ---------------------------------------------------------------------------
// K1b: Ap[b][o][q], Bqt[b][p][o] (with Cc folded in), W3bf (block 0).
// ---------------------------------------------------------------------------
__global__ __launch_bounds__(256) void k1b_planes(const float* __restrict__ W3,
        const float* __restrict__ b3, const float* __restrict__ RS1t,
        const float* __restrict__ CS1p, float* __restrict__ Ap,
        float* __restrict__ Bqt, unsigned short* __restrict__ W3bf) {
    int bx = blockIdx.x;
    int b = bx >> 2, og = bx & 3;
    int tid = threadIdx.x;
    __shared__ float cs_g[64][132];
    __shared__ float rs_g[64][132];
    __shared__ float s1_96[32];
    for (int k = tid; k < 64 * 128; k += 256) {
        int r = k >> 7, q = k & 127;
        int ch_c = (r < 32) ? (32 + r) : (64 + r);
        float s = 0.f;
        #pragma unroll
        for (int s8 = 0; s8 < NSTRIP; ++s8)
            s += CS1p[((size_t)(b * NSTRIP + s8) * NCH + ch_c) * PP + q];
        cs_g[r][q] = s;
    }
    for (int k = tid; k < 64 * 128; k += 256) {
        int p = k >> 6, r = k & 63;
        rs_g[r][p] = RS1t[((size_t)b * PP + p) * NCH + 64 + r];
    }
    __syncthreads();
    if (tid < 32) {
        float s = 0.f;
        for (int q = 0; q < 128; ++q) s += cs_g[32 + tid][q];
        s1_96[tid] = s;
    }
    int o = og * 32 + (tid >> 3), qh = tid & 7;
    {
        float wa[64];
        #pragma unroll
        for (int r = 0; r < 64; ++r)
            wa[r] = (r < 32) ? W3[o * NCH + 32 + r] * (1.f / 3.f)
                             : -W3[o * NCH + 64 + r] * (1.f / 9.f);
        #pragma unroll
        for (int j = 0; j < 4; ++j) {
            int q = qh * 16 + j * 4;
            float4 a = {0.f, 0.f, 0.f, 0.f};
            #pragma unroll
            for (int r = 0; r < 64; ++r) {
                float4 cv = *(const float4*)&cs_g[r][q];
                a.x = fmaf(wa[r], cv.x, a.x);
                a.y = fmaf(wa[r], cv.y, a.y);
                a.z = fmaf(wa[r], cv.z, a.z);
                a.w = fmaf(wa[r], cv.w, a.w);
            }
            *(float4*)&Ap[((size_t)b * NCH + o) * PP + q] = a;
        }
    }
    __syncthreads();
    float cc = b3[o];
    #pragma unroll
    for (int r = 0; r < 32; ++r)
        cc = fmaf(W3[o * NCH + 96 + r] * (1.f / 9.f), s1_96[r], cc);
    {
        float wb[64];
        #pragma unroll
        for (int r = 0; r < 64; ++r)
            wb[r] = (r < 32) ? W3[o * NCH + 64 + r] * (1.f / 3.f)
                             : -W3[o * NCH + 64 + r] * (1.f / 9.f);
        #pragma unroll
        for (int j = 0; j < 4; ++j) {
            int p4 = qh * 16 + j * 4;
            float4 a = {0.f, 0.f, 0.f, 0.f};
            #pragma unroll
            for (int r = 0; r < 64; ++r) {
                float4 rv = *(const float4*)&rs_g[r][p4];
                a.x = fmaf(wb[r], rv.x, a.x);
                a.y = fmaf(wb[r], rv.y, a.y);
                a.z = fmaf(wb[r], rv.z, a.z);
                a.w = fmaf(wb[r], rv.w, a.w);
            }
            Bqt[((size_t)b * PP + p4 + 0) * NCH + o] = a.x + cc;
            Bqt[((size_t)b * PP + p4 + 1) * NCH + o] = a.y + cc;
            Bqt[((size_t)b * PP + p4 + 2) * NCH + o] = a.z + cc;
            Bqt[((size_t)b * PP + p4 + 3) * NCH + o] = a.w + cc;
        }
    }
    if (bx == 0) {
        for (int i = 0; i < 16; ++i) {
            int k = tid + i * 256;
            float4 w = *(const float4*)(W3 + k * 4);
            int c0 = (k * 4) & 127;
            float sc = (c0 < 32) ? 1.f : ((c0 < 96) ? (-1.f / 3.f) : (1.f / 9.f));
            unsigned int lo = pk2(w.x * sc, w.y * sc);
            unsigned int hi = pk2(w.z * sc, w.w * sc);
            uint2 u = {lo, hi};
            *(uint2*)(W3bf + k * 4) = u;
        }
    }
}

// ---------------------------------------------------------------------------
// K2: SLIM MFMA kernel (unchanged from R9 — spill-free, Ap hoisted).
// ---------------------------------------------------------------------------
__global__ __launch_bounds__(512, 4) void k2_mfma(const float* __restrict__ phi,
        const float* __restrict__ W1, const float* __restrict__ b1,
        const unsigned short* __restrict__ W3bf,
        const float* __restrict__ Ap, const float* __restrict__ Bqt,
        unsigned short* __restrict__ v2) {
    int bx = blockIdx.x;
    int b = bx >> 4, strip = bx & 15;
    int p0 = strip * 8;
    __shared__ unsigned short w3_l[16384];
    __shared__ unsigned short t_l[16384];
    __shared__ unsigned short phi_b[2][1024];
    __shared__ float BC_l[2][128];
    int tid = threadIdx.x;
    int wv = tid >> 6, l = tid & 63, lr = l & 15, lg = l >> 4;
    int q0 = wv * 16 + lg * 4;

    #pragma unroll
    for (int i = 0; i < 4; ++i) {
        int k = tid + i * 512;
        int o = k >> 4, cb = (k & 15) * 16;
        bf16x8 v = *(const bf16x8*)(W3bf + k * 8);
        *(bf16x8*)((char*)w3_l + SWZB(o, cb)) = v;
    }
    bf16x8 w1fr = {0, 0, 0, 0, 0, 0, 0, 0};
    if (lg == 0) {
        int cc = wv * 16 + lr;
        float4 wa = *(const float4*)(W1 + cc * 8);
        float4 wb = *(const float4*)(W1 + cc * 8 + 4);
        w1fr[0] = (short)f2bf(wa.x); w1fr[1] = (short)f2bf(wa.y);
        w1fr[2] = (short)f2bf(wa.z); w1fr[3] = (short)f2bf(wa.w);
        w1fr[4] = (short)f2bf(wb.x); w1fr[5] = (short)f2bf(wb.y);
        w1fr[6] = (short)f2bf(wb.z); w1fr[7] = (short)f2bf(wb.w);
    }
    int c0 = wv * 16 + lg * 4;
    f32x4 binit = {b1[c0], b1[c0 + 1], b1[c0 + 2], b1[c0 + 3]};
    f32x4 apr[8];
    #pragma unroll
    for (int nt = 0; nt < 8; ++nt)
        apr[nt] = *(const f32x4*)(Ap + ((size_t)(b * NCH + nt * 16 + lr)) * PP + q0);
    if (tid < 128) {
        bf16x8 pv;
        #pragma unroll
        for (int ci = 0; ci < 8; ++ci)
            pv[ci] = (short)f2bf(phi[((size_t)(b * CIN + ci) * PP + p0) * PP + tid]);
        *(bf16x8*)(phi_b[0] + tid * 8) = pv;
        BC_l[0][tid] = Bqt[((size_t)b * PP + p0) * NCH + tid];
    }
    __syncthreads();

    for (int r = 0; r < 8; ++r) {
        int cur = r & 1, nxt = cur ^ 1;
        int p = p0 + r;
        float pfv[8]; float bcn = 0.f;
        if (r < 7 && tid < 128) {
            #pragma unroll
            for (int ci = 0; ci < 8; ++ci)
                pfv[ci] = phi[((size_t)(b * CIN + ci) * PP + p + 1) * PP + tid];
            bcn = Bqt[((size_t)b * PP + p + 1) * NCH + tid];
        }
        const unsigned short* pb = phi_b[cur];
        #pragma unroll
        for (int pt = 0; pt < 8; ++pt) {
            int pix = pt * 16 + lr;
            bf16x8 bfr1 = {0, 0, 0, 0, 0, 0, 0, 0};
            if (lg == 0) bfr1 = *(const bf16x8*)(pb + pix * 8);
            f32x4 a = __builtin_amdgcn_mfma_f32_16x16x32_bf16(w1fr, bfr1, binit, 0, 0, 0);
            uint2 u;
            u.x = pk2(fmaxf(a.x, 0.f), fmaxf(a.y, 0.f));
            u.y = pk2(fmaxf(a.z, 0.f), fmaxf(a.w, 0.f));
            *(uint2*)((char*)t_l + SWZB(pix, c0 * 2)) = u;
        }
        __syncthreads();                     // (A) t_l ready
        bf16x8 afr[4];
        #pragma unroll
        for (int ks = 0; ks < 4; ++ks)
            afr[ks] = *(const bf16x8*)((char*)t_l + SWZB(wv * 16 + lr, ks * 64 + lg * 16));
        __syncthreads();                     // (B) afr reads done -> t_l reusable
        #pragma unroll
        for (int nt = 0; nt < 8; ++nt) {
            int o = nt * 16 + lr;
            bf16x8 bfr[4];
            #pragma unroll
            for (int ks = 0; ks < 4; ++ks)
                bfr[ks] = *(const bf16x8*)((char*)w3_l + SWZB(o, ks * 64 + lg * 16));
            f32x4 acc = apr[nt] + BC_l[cur][o];
            #pragma unroll
            for (int ks = 0; ks < 4; ++ks)
                acc = __builtin_amdgcn_mfma_f32_16x16x32_bf16(afr[ks], bfr[ks], acc, 0, 0, 0);
            uint2 u;
            u.x = pk2(fmaxf(acc.x, 0.f), fmaxf(acc.y, 0.f));
            u.y = pk2(fmaxf(acc.z, 0.f), fmaxf(acc.w, 0.f));
            *(uint2*)((char*)t_l + SWZB(o, q0 * 2)) = u;
        }
        if (r < 7 && tid < 128) {
            bf16x8 pv;
            #pragma unroll
            for (int ci = 0; ci < 8; ++ci) pv[ci] = (short)f2bf(pfv[ci]);
            *(bf16x8*)(phi_b[nxt] + tid * 8) = pv;
            BC_l[nxt][tid] = bcn;
        }
        __syncthreads();                     // (C) v_l complete + next phi ready
        #pragma unroll
        for (int i = 0; i < 4; ++i) {
            int k = tid + i * 512;
            int o = k >> 4, j = k & 15;
            bf16x8 v = *(const bf16x8*)((char*)t_l + SWZB(o, j * 16));
            *(bf16x8*)(v2 + ((size_t)(b * NCH + o) * PP + p) * PP + j * 8) = v;
        }
        __syncthreads();                     // (D) v_l reads done before next GEMM1
    }
}

// ---------------------------------------------------------------------------
// K3: self-contained sums + postprocess (unchanged from R9).
// ---------------------------------------------------------------------------
__global__ __launch_bounds__(256) void k3_out(const unsigned short* __restrict__ v2,
        float* __restrict__ out) {
    int bx = blockIdx.x;
    int b = bx >> 7, ch = bx & 127;
    int g = ch >> 5;
    __shared__ unsigned short v_l[128 * 136];
    __shared__ float rs_l[128], cs_l[128];
    __shared__ float s_sh;
    int tid = threadIdx.x;
    size_t base = (size_t)(b * NCH + ch) * (PP * PP);
    const unsigned short* src = v2 + base;
    #pragma unroll
    for (int i = 0; i < 8; ++i) {
        int k = tid + i * 256;
        int pr = k >> 4, c8 = k & 15;
        *(bf16x8*)(v_l + pr * 136 + c8 * 8) = *(const bf16x8*)(src + k * 8);
    }
    __syncthreads();
    if (tid < 128) {
        float s = 0.f;
        #pragma unroll 4
        for (int j = 0; j < 16; ++j) {
            bf16x8 u = *(const bf16x8*)(v_l + tid * 136 + j * 8);
            #pragma unroll
            for (int e = 0; e < 8; ++e) s += bf2f((unsigned short)u[e]);
        }
        rs_l[tid] = s;
    } else {
        int q = tid - 128;
        float s = 0.f;
        for (int pr = 0; pr < 128; ++pr) s += bf2f(v_l[pr * 136 + q]);
        cs_l[q] = s;
    }
    __syncthreads();
    if (tid < 64) {
        float s = rs_l[tid] + rs_l[tid + 64];
        #pragma unroll
        for (int off = 32; off > 0; off >>= 1) s += __shfl_down(s, off);
        if (tid == 0) s_sh = s;
    }
    __syncthreads();
    float stot = s_sh;
    float* dst = out + base;
    #pragma unroll
    for (int i = 0; i < 8; ++i) {
        int k = tid + i * 256;
        int pr = k >> 4, q0 = (k & 15) * 8;
        bf16x8 u = *(const bf16x8*)(v_l + pr * 136 + q0);
        float rp = rs_l[pr];
        float o8[8];
        #pragma unroll
        for (int e = 0; e < 8; ++e) {
            float v = bf2f((unsigned short)u[e]);
            float cq = cs_l[q0 + e];
            float r;
            if (g == 0)      r = v;
            else if (g == 1) r = (cq - v) * (1.f / 3.f);
            else if (g == 2) r = (rp - v) * (1.f / 3.f);
            else             r = ((stot - rp) - cq + v) * (1.f / 9.f);
            o8[e] = r;
        }
        f32x4 lo = {o8[0], o8[1], o8[2], o8[3]};
        f32x4 hi = {o8[4], o8[5], o8[6], o8[7]};
        *(f32x4*)(dst + pr * PP + q0)     = lo;
        *(f32x4*)(dst + pr * PP + q0 + 4) = hi;
    }
}

// ---------------------------------------------------------------------------
extern "C" void kernel_launch(void* const* d_in, const int* in_sizes, int n_in,
                              void* d_out, int out_size, void* d_ws, size_t ws_size,
                              hipStream_t stream) {
    (void)in_sizes; (void)n_in; (void)out_size; (void)ws_size;
    const float* phi = (const float*)d_in[0];
    const float* W1  = (const float*)d_in[1];
    const float* b1  = (const float*)d_in[2];
    const float* W3  = (const float*)d_in[3];
    const float* b3  = (const float*)d_in[4];
    float* out = (float*)d_out;

    char* ws = (char*)d_ws;
    size_t off = 0;
    unsigned short* v2 = (unsigned short*)(ws + off); off += (size_t)BATCH * NCH * PP * PP * 2; // 134 MB
    float* RS1t = (float*)(ws + off); off += (size_t)BATCH * NCH * PP * 4;            // 2 MB
    float* CS1p = (float*)(ws + off); off += (size_t)BATCH * NSTRIP * NCH * PP * 4;   // 16 MB
    float* Ap   = (float*)(ws + off); off += (size_t)BATCH * NCH * PP * 4;            // 8 MB
    float* Bqt  = (float*)(ws + off); off += (size_t)BATCH * NCH * PP * 4;            // 8 MB
    unsigned short* W3bf = (unsigned short*)(ws + off); off += (size_t)NCH * NCH * 2; // 32 KB

    k1_sums<<<BATCH * NSTRIP, 512, 0, stream>>>(phi, W1, b1, RS1t, CS1p);
    k1b_planes<<<BATCH * 4, 256, 0, stream>>>(W3, b3, RS1t, CS1p, Ap, Bqt, W3bf);
    k2_mfma<<<BATCH * KSTRIP, 512, 0, stream>>>(phi, W1, b1, W3bf, Ap, Bqt, v2);
    k3_out<<<BATCH * NCH, 256, 0, stream>>>(v2, out);
}